// Round 6
// baseline (206.344 us; speedup 1.0000x reference)
//
#include <hip/hip_runtime.h>
#include <hip/hip_fp16.h>
#include <math.h>

// Problem dims (fixed)
#define B     4096
#define NIN   512
#define L     16
#define N     512
#define K     32
#define NOUT  256
#define TOTAL (NIN + L * N)
#define NACT  (L * N)          // 8192 activation columns
#define BROWS 8                // batch rows per block
#define BLOCK 512
#define NROWS (L * N + NOUT)   // 8448 neuron rows (hidden + output)

typedef __attribute__((ext_vector_type(8))) unsigned short u16x8;

__device__ __forceinline__ float sigmoidf_fast(float z) {
    return 1.0f / (1.0f + __expf(-z));
}
__device__ __forceinline__ __half2 bch2(unsigned int u) {
    return __builtin_bit_cast(__half2, u);
}
__device__ __forceinline__ unsigned int h2u(float a, float b) {
    unsigned short lo = __builtin_bit_cast(unsigned short, __float2half(a));
    unsigned short hi = __builtin_bit_cast(unsigned short, __float2half(b));
    return ((unsigned int)hi << 16) | lo;
}

// ---- repack (coalesced: one lane per (row,k) element):
//  * stable-partition each row's 32 (idx,w) pairs: x-cols (c<NIN) first —
//    makes most gather steps wave-uniform in the main kernel
//  * weights: dup-half2, pre-scaled 1/256 for act-cols (int8 decode),
//    unscaled for x-cols (fp16 raw)
//  * bias correction: b' = b + 0.5 * sum_{act-cols} w  (centered int8 storage)
__global__ void repack_kernel(const float* __restrict__ W,
                              const int*   __restrict__ idx,
                              const float* __restrict__ b,
                              const float* __restrict__ W_out,
                              const float* __restrict__ b_out,
                              const int*   __restrict__ idx_out,
                              unsigned int*   __restrict__ wh2,
                              unsigned short* __restrict__ i16,
                              float* __restrict__ bq,
                              float* __restrict__ bqo)
{
    __shared__ int   tc[256];
    __shared__ float tw[256];
    const int t = threadIdx.x;
    const int r = blockIdx.x * 8 + (t >> 5);   // neuron row (8448 rows, grid exact)
    const int k = t & 31;

    const bool is_out = (r >= L * N);
    const int  ro     = r - L * N;
    const float w = is_out ? W_out[(size_t)ro * K + k] : W[(size_t)r * K + k];
    const int   c = is_out ? idx_out[(size_t)ro * K + k] : idx[(size_t)r * K + k];

    // stable partition within the 32-lane row group
    const int lane = threadIdx.x & 63;
    const unsigned long long bal = __ballot(c < NIN);
    const unsigned gm = (unsigned)(bal >> (lane & 32));
    const unsigned lowmask = (1u << (lane & 31)) - 1u;
    const int nx = __popc(gm);
    const int before_x = __popc(gm & lowmask);
    const int pos = (c < NIN) ? before_x : (nx + ((lane & 31) - before_x));
    const int base = t & ~31;
    tc[base + pos] = c;
    tw[base + pos] = w;
    __syncthreads();
    const int   sc = tc[t];
    const float sw = tw[t];

    const float weff = (sc < NIN) ? sw : sw * (1.0f / 256.0f);
    wh2[(size_t)r * K + k] = h2u(weff, weff);
    i16[(size_t)r * K + k] = (unsigned short)sc;

    float s = (sc >= NIN) ? 0.5f * sw : 0.0f;
    #pragma unroll
    for (int off = 1; off < 32; off <<= 1) s += __shfl_xor(s, off, 32);
    if (k == 0) {
        if (is_out) bqo[ro] = b_out[ro] + s;
        else        bq[r]   = b[r] + s;
    }
}

// act[i] = 8 batch rows of col (NIN+i) as biased int8 (u = (a-0.5)*256+128).
// xh[c]  = 8 batch rows of x col c as fp16 (full precision for N(0,1) inputs).
// LDS 64+8 = 72 KB -> 2 blocks/CU, grid 512 = all resident.
// Decode: v_perm builds fp16 (1024+u); pk_sub 1152 (=0x6480!) -> (u-128);
// weights pre-scaled by 1/256 at repack.
__global__ __launch_bounds__(BLOCK, 4)
void ffnet_kernel(const float* __restrict__ x,
                  const unsigned int*   __restrict__ wh2,
                  const unsigned short* __restrict__ i16,
                  const float* __restrict__ bq,
                  const float* __restrict__ bqo,
                  float* __restrict__ out)
{
    __shared__ uint2 act[NACT];   // 64 KB
    __shared__ uint4 xh[NIN];     // 8 KB

    const int t  = threadIdx.x;
    const int r0 = blockIdx.x * BROWS;

    // ---- stage x (fp16, 8 rows per column); thread t owns column t
    {
        float xv[8];
        #pragma unroll
        for (int rr = 0; rr < 8; ++rr)
            xv[rr] = x[(size_t)(r0 + rr) * NIN + t];
        uint4 v;
        v.x = h2u(xv[0], xv[1]);
        v.y = h2u(xv[2], xv[3]);
        v.z = h2u(xv[4], xv[5]);
        v.w = h2u(xv[6], xv[7]);
        xh[t] = v;
    }

    // ---- prefetch layer-0 indices (latency overlaps the barrier)
    u16x8 ni[4];
    {
        const u16x8* ip = (const u16x8*)(i16 + (size_t)t * K);
        ni[0] = ip[0]; ni[1] = ip[1]; ni[2] = ip[2]; ni[3] = ip[3];
    }
    __syncthreads();

#define GATHER1(C, W2)                                                          \
    {                                                                           \
        const int c_ = (C);                                                     \
        const __half2 w2_ = (W2);                                               \
        if (c_ < NIN) {                                                         \
            const uint4 v_ = xh[c_];                                            \
            a0 = __hfma2(bch2(v_.x), w2_, a0);                                  \
            a1 = __hfma2(bch2(v_.y), w2_, a1);                                  \
            a2 = __hfma2(bch2(v_.z), w2_, a2);                                  \
            a3 = __hfma2(bch2(v_.w), w2_, a3);                                  \
        } else {                                                                \
            const uint2 q_ = act[c_ - NIN];                                     \
            const unsigned d0_ = __builtin_amdgcn_perm(0x64646464u, q_.x, 0x05010400u); \
            const unsigned d1_ = __builtin_amdgcn_perm(0x64646464u, q_.x, 0x05030402u); \
            const unsigned d2_ = __builtin_amdgcn_perm(0x64646464u, q_.y, 0x05010400u); \
            const unsigned d3_ = __builtin_amdgcn_perm(0x64646464u, q_.y, 0x05030402u); \
            const __half2 bias_ = bch2(0x64806480u);  /* {1152,1152} = 1024+128 */ \
            a0 = __hfma2(__hsub2(bch2(d0_), bias_), w2_, a0);                   \
            a1 = __hfma2(__hsub2(bch2(d1_), bias_), w2_, a1);                   \
            a2 = __hfma2(__hsub2(bch2(d2_), bias_), w2_, a2);                   \
            a3 = __hfma2(__hsub2(bch2(d3_), bias_), w2_, a3);                   \
        }                                                                       \
    }

    // ---- 16 hidden layers; thread t = neuron t; one barrier per layer
    for (int l = 0; l < L; ++l) {
        u16x8 ci[4] = { ni[0], ni[1], ni[2], ni[3] };

        unsigned wu[32];
        {
            const uint4* wp = (const uint4*)(wh2 + ((size_t)l * N + t) * K);
            #pragma unroll
            for (int g = 0; g < 8; ++g) {
                const uint4 w4 = wp[g];
                wu[4*g] = w4.x; wu[4*g+1] = w4.y; wu[4*g+2] = w4.z; wu[4*g+3] = w4.w;
            }
        }
        const float bb = bq[l * N + t];

        if (l + 1 < L) {   // prefetch next layer's indices
            const u16x8* np = (const u16x8*)(i16 + ((size_t)(l + 1) * N + t) * K);
            ni[0] = np[0]; ni[1] = np[1]; ni[2] = np[2]; ni[3] = np[3];
        }

        __half2 a0 = bch2(0u), a1 = bch2(0u), a2 = bch2(0u), a3 = bch2(0u);
        #pragma unroll
        for (int g = 0; g < 4; ++g) {
            #pragma unroll
            for (int j = 0; j < 8; ++j)
                GATHER1((int)ci[g][j], bch2(wu[g * 8 + j]));
        }

        const float zf[8] = {
            __low2float(a0), __high2float(a0), __low2float(a1), __high2float(a1),
            __low2float(a2), __high2float(a2), __low2float(a3), __high2float(a3)
        };
        unsigned u8[8];
        #pragma unroll
        for (int rr = 0; rr < 8; ++rr) {
            const float a = sigmoidf_fast(zf[rr] + bb);
            u8[rr] = (unsigned)fminf(rintf(a * 256.0f), 255.0f);
        }
        uint2 pk;
        pk.x = u8[0] | (u8[1] << 8) | (u8[2] << 16) | (u8[3] << 24);
        pk.y = u8[4] | (u8[5] << 8) | (u8[6] << 16) | (u8[7] << 24);
        act[l * N + t] = pk;
        __syncthreads();
    }

    // ---- output layer: threads 0..NOUT-1, fp32 sigmoid out
    if (t < NOUT) {
        const u16x8* ip = (const u16x8*)(i16 + ((size_t)(L * N) + t) * K);
        u16x8 oi[4] = { ip[0], ip[1], ip[2], ip[3] };
        unsigned wu[32];
        {
            const uint4* wp = (const uint4*)(wh2 + ((size_t)(L * N) + t) * K);
            #pragma unroll
            for (int g = 0; g < 8; ++g) {
                const uint4 w4 = wp[g];
                wu[4*g] = w4.x; wu[4*g+1] = w4.y; wu[4*g+2] = w4.z; wu[4*g+3] = w4.w;
            }
        }
        __half2 a0 = bch2(0u), a1 = bch2(0u), a2 = bch2(0u), a3 = bch2(0u);
        #pragma unroll
        for (int g = 0; g < 4; ++g) {
            #pragma unroll
            for (int j = 0; j < 8; ++j)
                GATHER1((int)oi[g][j], bch2(wu[g * 8 + j]));
        }
        const float bb = bqo[t];
        const float zf[8] = {
            __low2float(a0), __high2float(a0), __low2float(a1), __high2float(a1),
            __low2float(a2), __high2float(a2), __low2float(a3), __high2float(a3)
        };
        #pragma unroll
        for (int rr = 0; rr < 8; ++rr)
            out[(size_t)(r0 + rr) * NOUT + t] = sigmoidf_fast(zf[rr] + bb);
    }
#undef GATHER1
}

extern "C" void kernel_launch(void* const* d_in, const int* in_sizes, int n_in,
                              void* d_out, int out_size, void* d_ws, size_t ws_size,
                              hipStream_t stream) {
    const float* x     = (const float*)d_in[0];   // (B, NIN)
    const float* W     = (const float*)d_in[1];   // (L, N, K)
    const float* b     = (const float*)d_in[2];   // (L, N)
    const float* W_out = (const float*)d_in[3];   // (NOUT, K)
    const float* b_out = (const float*)d_in[4];   // (NOUT,)
    const int*   idx   = (const int*)d_in[5];     // (L, N, K)
    const int*   idx_o = (const int*)d_in[6];     // (NOUT, K)
    float* out = (float*)d_out;                   // (B, NOUT)

    // workspace layout (~1.58 MB)
    char* ws = (char*)d_ws;
    unsigned int*   wh2  = (unsigned int*)  (ws);                       // 8448*32*4 = 1081344
    unsigned short* i16  = (unsigned short*)(ws + 1081344);             // 8448*32*2 =  540672
    float*          bq   = (float*)         (ws + 1081344 + 540672);    // 32768
    float*          bqo  = (float*)         (ws + 1081344 + 540672 + 32768); // 1024

    repack_kernel<<<dim3(NROWS / 8), dim3(256), 0, stream>>>(
        W, idx, b, W_out, b_out, idx_o, wh2, i16, bq, bqo);

    ffnet_kernel<<<dim3(B / BROWS), dim3(BLOCK), 0, stream>>>(
        x, wh2, i16, bq, bqo, out);
}

// Round 7
// 169.401 us; speedup vs baseline: 1.2181x; 1.2181x over previous
//
#include <hip/hip_runtime.h>
#include <hip/hip_fp16.h>
#include <math.h>

// Problem dims (fixed)
#define B     4096
#define NIN   512
#define L     16
#define N     512
#define K     32
#define NOUT  256
#define TOTAL (NIN + L * N)    // 8704 columns
#define BROWS 16               // batch rows per block (16 int8 bytes = one b128 column)
#define BLOCK 512
#define NROWS (L * N + NOUT)   // 8448 neuron rows
#define XQ    24.0f            // x quant scale: u = round(x*24)+128, range +-5.33

typedef __attribute__((ext_vector_type(8))) unsigned short u16x8;

__device__ __forceinline__ float sigmoidf_fast(float z) {
    return 1.0f / (1.0f + __expf(-z));
}
__device__ __forceinline__ __half2 bch2(unsigned int u) {
    return __builtin_bit_cast(__half2, u);
}
__device__ __forceinline__ unsigned int h2u(float a, float b) {
    unsigned short lo = __builtin_bit_cast(unsigned short, __float2half(a));
    unsigned short hi = __builtin_bit_cast(unsigned short, __float2half(b));
    return ((unsigned int)hi << 16) | lo;
}

// ---- repack (fully coalesced, no LDS, no reordering — kernel is branch-free
// so entry order is irrelevant):
//   w_eff = w * (c<NIN ? 1/XQ : 1/256), duplicated into half2
//   bias fold: b' = b + 0.5 * sum_{act-cols} w   (act stored biased at 128)
__global__ void repack_kernel(const float* __restrict__ W,
                              const int*   __restrict__ idx,
                              const float* __restrict__ b,
                              const float* __restrict__ W_out,
                              const float* __restrict__ b_out,
                              const int*   __restrict__ idx_out,
                              unsigned int*   __restrict__ wh2,
                              unsigned short* __restrict__ i16,
                              float* __restrict__ bq,
                              float* __restrict__ bqo)
{
    const int t = threadIdx.x;
    const int r = blockIdx.x * 8 + (t >> 5);   // neuron row; grid covers 8448 exactly
    const int k = t & 31;

    const bool is_out = (r >= L * N);
    const int  ro     = r - L * N;
    const float w = is_out ? W_out[(size_t)ro * K + k] : W[(size_t)r * K + k];
    const int   c = is_out ? idx_out[(size_t)ro * K + k] : idx[(size_t)r * K + k];

    const float weff = (c < NIN) ? w * (1.0f / XQ) : w * (1.0f / 256.0f);
    wh2[(size_t)r * K + k] = h2u(weff, weff);
    i16[(size_t)r * K + k] = (unsigned short)c;

    float s = (c >= NIN) ? 0.5f * w : 0.0f;
    #pragma unroll
    for (int off = 1; off < 32; off <<= 1) s += __shfl_xor(s, off, 32);
    if (k == 0) {
        if (is_out) bqo[ro] = b_out[ro] + s;
        else        bq[r]   = b[r] + s;
    }
}

// buf[c] = 16 batch rows of column c, one byte each (biased int8):
//   x cols:   u = round(x*XQ) + 128          -> value = (u-128)/XQ
//   act cols: u = round(a*256) clamp [0,255] -> value-0.5 = (u-128)/256
// Decode (per uint32, 4 rows): v_perm -> fp16 {1024+u0,1024+u1}, hsub 1152
// (0x6480) -> exact integer (u-128); weight pre-scaled at repack.
// One ds_read_b128 feeds 16 MACs; the gather loop is 32 identical
// branch-free steps -> compiler batches independent ds_reads (MLP),
// unlike R6's per-element divergent branch.
// LDS 136 KB -> 1 block/CU; grid 256 = one block per CU, single round.
__global__ __launch_bounds__(BLOCK, 2)
void ffnet_kernel(const float* __restrict__ x,
                  const unsigned int*   __restrict__ wh2,
                  const unsigned short* __restrict__ i16,
                  const float* __restrict__ bq,
                  const float* __restrict__ bqo,
                  float* __restrict__ out)
{
    __shared__ uint4 buf[TOTAL];   // 8704 * 16 B = 136 KB

    const int t  = threadIdx.x;
    const int r0 = blockIdx.x * BROWS;

    // ---- stage x (int8, 16 rows per column); thread t owns column t
    {
        unsigned u8[16];
        #pragma unroll
        for (int rr = 0; rr < 16; ++rr) {
            const float xv = x[(size_t)(r0 + rr) * NIN + t];
            const float q  = rintf(xv * XQ) + 128.0f;
            u8[rr] = (unsigned)fmaxf(0.0f, fminf(q, 255.0f));
        }
        uint4 v;
        v.x = u8[0]  | (u8[1]  << 8) | (u8[2]  << 16) | (u8[3]  << 24);
        v.y = u8[4]  | (u8[5]  << 8) | (u8[6]  << 16) | (u8[7]  << 24);
        v.z = u8[8]  | (u8[9]  << 8) | (u8[10] << 16) | (u8[11] << 24);
        v.w = u8[12] | (u8[13] << 8) | (u8[14] << 16) | (u8[15] << 24);
        buf[t] = v;
    }

    // ---- prefetch layer-0 indices (latency overlaps the barrier)
    u16x8 ni[4];
    {
        const u16x8* ip = (const u16x8*)(i16 + (size_t)t * K);
        ni[0] = ip[0]; ni[1] = ip[1]; ni[2] = ip[2]; ni[3] = ip[3];
    }
    __syncthreads();

    const __half2 dbias = bch2(0x64806480u);   // {1152,1152} = 1024+128

#define DECFMA(QW, A0, A1)                                                      \
    {                                                                           \
        const unsigned dlo_ = __builtin_amdgcn_perm(0x64646464u, (QW), 0x05010400u); \
        const unsigned dhi_ = __builtin_amdgcn_perm(0x64646464u, (QW), 0x05030402u); \
        (A0) = __hfma2(__hsub2(bch2(dlo_), dbias), w2_, (A0));                  \
        (A1) = __hfma2(__hsub2(bch2(dhi_), dbias), w2_, (A1));                  \
    }
#define GATHER1(C, W2)                                                          \
    {                                                                           \
        const __half2 w2_ = (W2);                                               \
        const uint4 q_ = buf[(C)];                                              \
        DECFMA(q_.x, a0, a1)                                                    \
        DECFMA(q_.y, a2, a3)                                                    \
        DECFMA(q_.z, a4, a5)                                                    \
        DECFMA(q_.w, a6, a7)                                                    \
    }

    // ---- 16 hidden layers; thread t = neuron t; one barrier per layer
    for (int l = 0; l < L; ++l) {
        u16x8 ci[4] = { ni[0], ni[1], ni[2], ni[3] };

        uint4 wq[8];
        {
            const uint4* wp = (const uint4*)(wh2 + ((size_t)l * N + t) * K);
            #pragma unroll
            for (int g = 0; g < 8; ++g) wq[g] = wp[g];
        }
        const float bb = bq[l * N + t];

        if (l + 1 < L) {   // prefetch next layer's indices
            const u16x8* np = (const u16x8*)(i16 + ((size_t)(l + 1) * N + t) * K);
            ni[0] = np[0]; ni[1] = np[1]; ni[2] = np[2]; ni[3] = np[3];
        }

        __half2 a0 = bch2(0u), a1 = bch2(0u), a2 = bch2(0u), a3 = bch2(0u),
                a4 = bch2(0u), a5 = bch2(0u), a6 = bch2(0u), a7 = bch2(0u);
        #pragma unroll
        for (int g = 0; g < 4; ++g) {
            const uint4 wa = wq[2 * g], wb = wq[2 * g + 1];
            GATHER1((int)ci[g][0], bch2(wa.x));
            GATHER1((int)ci[g][1], bch2(wa.y));
            GATHER1((int)ci[g][2], bch2(wa.z));
            GATHER1((int)ci[g][3], bch2(wa.w));
            GATHER1((int)ci[g][4], bch2(wb.x));
            GATHER1((int)ci[g][5], bch2(wb.y));
            GATHER1((int)ci[g][6], bch2(wb.z));
            GATHER1((int)ci[g][7], bch2(wb.w));
        }

        const __half2 av[8] = {a0, a1, a2, a3, a4, a5, a6, a7};
        unsigned u8[16];
        #pragma unroll
        for (int p = 0; p < 8; ++p) {
            const float z0 = __low2float(av[p])  + bb;
            const float z1 = __high2float(av[p]) + bb;
            const float s0 = sigmoidf_fast(z0);
            const float s1 = sigmoidf_fast(z1);
            u8[2*p]   = (unsigned)fminf(rintf(s0 * 256.0f), 255.0f);
            u8[2*p+1] = (unsigned)fminf(rintf(s1 * 256.0f), 255.0f);
        }
        uint4 pk;
        pk.x = u8[0]  | (u8[1]  << 8) | (u8[2]  << 16) | (u8[3]  << 24);
        pk.y = u8[4]  | (u8[5]  << 8) | (u8[6]  << 16) | (u8[7]  << 24);
        pk.z = u8[8]  | (u8[9]  << 8) | (u8[10] << 16) | (u8[11] << 24);
        pk.w = u8[12] | (u8[13] << 8) | (u8[14] << 16) | (u8[15] << 24);
        buf[NIN + l * N + t] = pk;
        __syncthreads();
    }

    // ---- output layer: threads 0..NOUT-1, fp32 sigmoid out
    if (t < NOUT) {
        const u16x8* ip = (const u16x8*)(i16 + ((size_t)(L * N) + t) * K);
        u16x8 oi[4] = { ip[0], ip[1], ip[2], ip[3] };
        uint4 wq[8];
        {
            const uint4* wp = (const uint4*)(wh2 + ((size_t)(L * N) + t) * K);
            #pragma unroll
            for (int g = 0; g < 8; ++g) wq[g] = wp[g];
        }
        __half2 a0 = bch2(0u), a1 = bch2(0u), a2 = bch2(0u), a3 = bch2(0u),
                a4 = bch2(0u), a5 = bch2(0u), a6 = bch2(0u), a7 = bch2(0u);
        #pragma unroll
        for (int g = 0; g < 4; ++g) {
            const uint4 wa = wq[2 * g], wb = wq[2 * g + 1];
            GATHER1((int)oi[g][0], bch2(wa.x));
            GATHER1((int)oi[g][1], bch2(wa.y));
            GATHER1((int)oi[g][2], bch2(wa.z));
            GATHER1((int)oi[g][3], bch2(wa.w));
            GATHER1((int)oi[g][4], bch2(wb.x));
            GATHER1((int)oi[g][5], bch2(wb.y));
            GATHER1((int)oi[g][6], bch2(wb.z));
            GATHER1((int)oi[g][7], bch2(wb.w));
        }
        const float bb = bqo[t];
        const __half2 av[8] = {a0, a1, a2, a3, a4, a5, a6, a7};
        #pragma unroll
        for (int p = 0; p < 8; ++p) {
            out[(size_t)(r0 + 2*p)     * NOUT + t] = sigmoidf_fast(__low2float(av[p])  + bb);
            out[(size_t)(r0 + 2*p + 1) * NOUT + t] = sigmoidf_fast(__high2float(av[p]) + bb);
        }
    }
#undef GATHER1
#undef DECFMA
}

extern "C" void kernel_launch(void* const* d_in, const int* in_sizes, int n_in,
                              void* d_out, int out_size, void* d_ws, size_t ws_size,
                              hipStream_t stream) {
    const float* x     = (const float*)d_in[0];   // (B, NIN)
    const float* W     = (const float*)d_in[1];   // (L, N, K)
    const float* b     = (const float*)d_in[2];   // (L, N)
    const float* W_out = (const float*)d_in[3];   // (NOUT, K)
    const float* b_out = (const float*)d_in[4];   // (NOUT,)
    const int*   idx   = (const int*)d_in[5];     // (L, N, K)
    const int*   idx_o = (const int*)d_in[6];     // (NOUT, K)
    float* out = (float*)d_out;                   // (B, NOUT)

    // workspace layout (~1.58 MB)
    char* ws = (char*)d_ws;
    unsigned int*   wh2 = (unsigned int*)  (ws);                             // 8448*32*4
    unsigned short* i16 = (unsigned short*)(ws + 1081344);                   // 8448*32*2
    float*          bq  = (float*)         (ws + 1081344 + 540672);          // 32 KB
    float*          bqo = (float*)         (ws + 1081344 + 540672 + 32768);  // 1 KB

    repack_kernel<<<dim3(NROWS / 8), dim3(256), 0, stream>>>(
        W, idx, b, W_out, b_out, idx_o, wh2, i16, bq, bqo);

    ffnet_kernel<<<dim3(B / BROWS), dim3(BLOCK), 0, stream>>>(
        x, wh2, i16, bq, bqo, out);
}